// Round 8
// baseline (5991.270 us; speedup 1.0000x reference)
//
#include <hip/hip_runtime.h>

#define T_STEPS 8192
#define BATCH   128
#define HID     96

__device__ __forceinline__ float fast_sigmoid(float v) {
    return __builtin_amdgcn_rcpf(1.0f + __expf(-v));
}
__device__ __forceinline__ float fast_tanh(float v) {   // 2*sigmoid(2v)-1
    return fmaf(2.0f, __builtin_amdgcn_rcpf(1.0f + __expf(-2.0f * v)), -1.0f);
}

// R1-proven residency pattern: NAMED const float4 loads straight from W_hh,
// consumed via fmaf on components (R1: VGPR=124, weights stayed register-
// resident; every f16/cvt/prepack variant R3-R6 got sunk back into the loop).
#define WGATE(g) \
    const float4* wp##g = reinterpret_cast<const float4*>(W_hh + ((g) * HID + j) * HID) + q * 6; \
    const float4 w##g##_0 = wp##g[0]; \
    const float4 w##g##_1 = wp##g[1]; \
    const float4 w##g##_2 = wp##g[2]; \
    const float4 w##g##_3 = wp##g[3]; \
    const float4 w##g##_4 = wp##g[4]; \
    const float4 w##g##_5 = wp##g[5];

#define FMA4(hh, ww, A) { \
    A = fmaf(hh.x, ww.x, A); A = fmaf(hh.y, ww.y, A); \
    A = fmaf(hh.z, ww.z, A); A = fmaf(hh.w, ww.w, A); }

#define DOTG(g, A) \
    FMA4(h0, w##g##_0, A) FMA4(h1, w##g##_1, A) FMA4(h2, w##g##_2, A) \
    FMA4(h3, w##g##_3, A) FMA4(h4, w##g##_4, A) FMA4(h5, w##g##_5, A)

__global__ __launch_bounds__(448, 2)
void lstm_seq_kernel(const float* __restrict__ x,
                     const float* __restrict__ W_ih,
                     const float* __restrict__ W_hh,
                     const float* __restrict__ b_ih,
                     const float* __restrict__ b_hh,
                     const float* __restrict__ W_fc,
                     const float* __restrict__ b_fc,
                     float* __restrict__ out)
{
    const int b   = blockIdx.x;
    const int tid = threadIdx.x;   // 0..447: waves 0-5 = dot workers, wave 6 = FC

    __shared__ __align__(16) float h_buf[2][HID];   // double-buffered hidden state, f32

    if (tid < HID) { h_buf[0][tid] = 0.0f; h_buf[1][tid] = 0.0f; }
    __syncthreads();

    if (tid < 384) {
        // ---- worker: unit j = tid>>2 owns gates i,f,g,o over K-slice q = tid&3 (24 wide) ----
        const int j = tid >> 2;
        const int q = tid & 3;

        WGATE(0) WGATE(1) WGATE(2) WGATE(3)   // 24 float4 = 96 VGPRs of f32 weights

        const float wih0 = W_ih[0 * HID + j], bs0 = b_ih[0 * HID + j] + b_hh[0 * HID + j];
        const float wih1 = W_ih[1 * HID + j], bs1 = b_ih[1 * HID + j] + b_hh[1 * HID + j];
        const float wih2 = W_ih[2 * HID + j], bs2 = b_ih[2 * HID + j] + b_hh[2 * HID + j];
        const float wih3 = W_ih[3 * HID + j], bs3 = b_ih[3 * HID + j] + b_hh[3 * HID + j];

        float c  = 0.0f;               // replicated across the quad (identical values)
        float xt = x[0 * BATCH + b];

        for (int t = 0; t < T_STEPS; ++t) {
            const int   tn    = (t + 1 < T_STEPS) ? (t + 1) : t;
            const float xnext = x[tn * BATCH + b];            // uniform prefetch

            // this thread's 24-float slice of h: 6 ds_read_b128, conflict-free
            // (4 distinct 16B regions per inst, 16-lane broadcast each)
            const float4* hv = reinterpret_cast<const float4*>(&h_buf[t & 1][q * 24]);
            const float4 h0 = hv[0], h1 = hv[1], h2 = hv[2];
            const float4 h3 = hv[3], h4 = hv[4], h5 = hv[5];

            float ai = (q == 0) ? fmaf(xt, wih0, bs0) : 0.0f;
            float af = (q == 0) ? fmaf(xt, wih1, bs1) : 0.0f;
            float ag = (q == 0) ? fmaf(xt, wih2, bs2) : 0.0f;
            float ao = (q == 0) ? fmaf(xt, wih3, bs3) : 0.0f;
            DOTG(0, ai) DOTG(1, af) DOTG(2, ag) DOTG(3, ao)

            // quad reduce (xor1 + xor2 -> DPP quad_perm): full 96-sums in all 4 lanes
            float si = ai + __shfl_xor(ai, 1); si += __shfl_xor(si, 2);
            float sf = af + __shfl_xor(af, 1); sf += __shfl_xor(sf, 2);
            float sg = ag + __shfl_xor(ag, 1); sg += __shfl_xor(sg, 2);
            float so = ao + __shfl_xor(ao, 1); so += __shfl_xor(so, 2);

            const float gi = fast_sigmoid(si);
            const float gf = fast_sigmoid(sf);
            const float gg = fast_tanh(sg);
            const float go = fast_sigmoid(so);
            c = fmaf(gf, c, gi * gg);
            const float hn = go * fast_tanh(c);

            if (q == 0) h_buf[(t & 1) ^ 1][j] = hn;   // 16 consecutive floats per wave
            __syncthreads();
            xt = xnext;
        }
    } else {
        // -------- FC wave: out[t-1] = h_t . W_fc + b_fc + x[t-1], one step deferred --------
        const int   lane = tid - 384;
        const float wfa  = W_fc[lane];
        const float wfb  = (lane < 32) ? W_fc[64 + lane] : 0.0f;
        const float bfc  = b_fc[0];

        float xfc = x[b];                                     // x[(t-1)] for t=1
        for (int t = 0; t < T_STEPS; ++t) {
            const float xnext = x[t * BATCH + b];             // becomes xfc for iter t+1
            if (t > 0) {
                const float* hb = h_buf[t & 1];               // h_t
                float s = hb[lane] * wfa;
                if (lane < 32) s = fmaf(hb[64 + lane], wfb, s);
                #pragma unroll
                for (int d = 1; d < 64; d <<= 1) s += __shfl_xor(s, d);
                if (lane == 0) out[(t - 1) * BATCH + b] = s + bfc + xfc;
            }
            __syncthreads();
            xfc = xnext;
        }
        {   // final timestep: h_T is in h_buf[T&1] (T even -> buf 0)
            const float* hb = h_buf[T_STEPS & 1];
            float s = hb[lane] * wfa;
            if (lane < 32) s = fmaf(hb[64 + lane], wfb, s);
            #pragma unroll
            for (int d = 1; d < 64; d <<= 1) s += __shfl_xor(s, d);
            if (lane == 0) out[(T_STEPS - 1) * BATCH + b] = s + bfc + xfc;
        }
    }
}

extern "C" void kernel_launch(void* const* d_in, const int* in_sizes, int n_in,
                              void* d_out, int out_size, void* d_ws, size_t ws_size,
                              hipStream_t stream) {
    (void)in_sizes; (void)n_in; (void)out_size; (void)d_ws; (void)ws_size;
    const float* x    = (const float*)d_in[0];
    const float* W_ih = (const float*)d_in[1];
    const float* W_hh = (const float*)d_in[2];
    const float* b_ih = (const float*)d_in[3];
    const float* b_hh = (const float*)d_in[4];
    const float* W_fc = (const float*)d_in[5];
    const float* b_fc = (const float*)d_in[6];
    float* out = (float*)d_out;

    lstm_seq_kernel<<<dim3(BATCH), dim3(448), 0, stream>>>(
        x, W_ih, W_hh, b_ih, b_hh, W_fc, b_fc, out);
}

// Round 9
// 5784.369 us; speedup vs baseline: 1.0358x; 1.0358x over previous
//
#include <hip/hip_runtime.h>

#define T_STEPS 8192
#define BATCH   128
#define HID     96

__device__ __forceinline__ float fast_sigmoid(float v) {
    return __builtin_amdgcn_rcpf(1.0f + __expf(-v));
}
__device__ __forceinline__ float fast_tanh(float v) {   // 2*sigmoid(2v)-1
    return fmaf(2.0f, __builtin_amdgcn_rcpf(1.0f + __expf(-2.0f * v)), -1.0f);
}

#define WGATE(g) \
    const float4* wp##g = reinterpret_cast<const float4*>(W_hh + ((g) * HID + j) * HID) + q * 6; \
    const float4 w##g##_0 = wp##g[0]; \
    const float4 w##g##_1 = wp##g[1]; \
    const float4 w##g##_2 = wp##g[2]; \
    const float4 w##g##_3 = wp##g[3]; \
    const float4 w##g##_4 = wp##g[4]; \
    const float4 w##g##_5 = wp##g[5];

#define FMA4(hh, ww, A) { \
    A = fmaf(hh.x, ww.x, A); A = fmaf(hh.y, ww.y, A); \
    A = fmaf(hh.z, ww.z, A); A = fmaf(hh.w, ww.w, A); }

// Residency fix (R0-R7 post-mortem): __launch_bounds__ 2nd arg sets only the MIN
// waves/EU; LLVM's scheduler still raises occupancy opportunistically by
// rematerializing loop-invariant weight loads into the loop (VGPR 68-72 every
// round, ~25 TB/s L2 re-reads). amdgpu_waves_per_eu(1,2) pins the MAX too:
// budget 256 VGPR, no occupancy reward for remat -> weights stay resident.
__global__ __attribute__((amdgpu_flat_work_group_size(448, 448), amdgpu_waves_per_eu(1, 2)))
void lstm_seq_kernel(const float* __restrict__ x,
                     const float* __restrict__ W_ih,
                     const float* __restrict__ W_hh,
                     const float* __restrict__ b_ih,
                     const float* __restrict__ b_hh,
                     const float* __restrict__ W_fc,
                     const float* __restrict__ b_fc,
                     float* __restrict__ out)
{
    const int b   = blockIdx.x;
    const int tid = threadIdx.x;   // 0..447: waves 0-5 = dot workers, wave 6 = FC

    __shared__ __align__(16) float h_buf[2][HID];   // double-buffered hidden state, f32

    if (tid < HID) { h_buf[0][tid] = 0.0f; h_buf[1][tid] = 0.0f; }
    __syncthreads();

    if (tid < 384) {
        // ---- worker: unit j = tid>>2 owns gates i,f,g,o over K-slice q = tid&3 (24 wide) ----
        const int j = tid >> 2;
        const int q = tid & 3;

        WGATE(0) WGATE(1) WGATE(2) WGATE(3)   // 24 float4 = 96 VGPRs of f32 weights

        const float wih0 = W_ih[0 * HID + j], bs0 = b_ih[0 * HID + j] + b_hh[0 * HID + j];
        const float wih1 = W_ih[1 * HID + j], bs1 = b_ih[1 * HID + j] + b_hh[1 * HID + j];
        const float wih2 = W_ih[2 * HID + j], bs2 = b_ih[2 * HID + j] + b_hh[2 * HID + j];
        const float wih3 = W_ih[3 * HID + j], bs3 = b_ih[3 * HID + j] + b_hh[3 * HID + j];

        float c  = 0.0f;               // replicated across the quad (identical values)
        float xt = x[0 * BATCH + b];

        for (int t = 0; t < T_STEPS; ++t) {
            const int   tn    = (t + 1 < T_STEPS) ? (t + 1) : t;
            const float xnext = x[tn * BATCH + b];            // uniform prefetch

            const float4* hv = reinterpret_cast<const float4*>(&h_buf[t & 1][q * 24]);

            float ai = (q == 0) ? fmaf(xt, wih0, bs0) : 0.0f;
            float af = (q == 0) ? fmaf(xt, wih1, bs1) : 0.0f;
            float ag = (q == 0) ? fmaf(xt, wih2, bs2) : 0.0f;
            float ao = (q == 0) ? fmaf(xt, wih3, bs3) : 0.0f;

            // ---- half 1: h elems [0,12) of this slice (3 float4 live, caps pressure) ----
            {
                const float4 h0 = hv[0], h1 = hv[1], h2 = hv[2];
                FMA4(h0, w0_0, ai) FMA4(h1, w0_1, ai) FMA4(h2, w0_2, ai)
                FMA4(h0, w1_0, af) FMA4(h1, w1_1, af) FMA4(h2, w1_2, af)
                FMA4(h0, w2_0, ag) FMA4(h1, w2_1, ag) FMA4(h2, w2_2, ag)
                FMA4(h0, w3_0, ao) FMA4(h1, w3_1, ao) FMA4(h2, w3_2, ao)
            }
            // ---- half 2: h elems [12,24) ----
            {
                const float4 h3 = hv[3], h4 = hv[4], h5 = hv[5];
                FMA4(h3, w0_3, ai) FMA4(h4, w0_4, ai) FMA4(h5, w0_5, ai)
                FMA4(h3, w1_3, af) FMA4(h4, w1_4, af) FMA4(h5, w1_5, af)
                FMA4(h3, w2_3, ag) FMA4(h4, w2_4, ag) FMA4(h5, w2_5, ag)
                FMA4(h3, w3_3, ao) FMA4(h4, w3_4, ao) FMA4(h5, w3_5, ao)
            }

            // quad reduce (xor1 + xor2 -> DPP quad_perm): full 96-sums in all 4 lanes
            float si = ai + __shfl_xor(ai, 1); si += __shfl_xor(si, 2);
            float sf = af + __shfl_xor(af, 1); sf += __shfl_xor(sf, 2);
            float sg = ag + __shfl_xor(ag, 1); sg += __shfl_xor(sg, 2);
            float so = ao + __shfl_xor(ao, 1); so += __shfl_xor(so, 2);

            const float gi = fast_sigmoid(si);
            const float gf = fast_sigmoid(sf);
            const float gg = fast_tanh(sg);
            const float go = fast_sigmoid(so);
            c = fmaf(gf, c, gi * gg);
            const float hn = go * fast_tanh(c);

            if (q == 0) h_buf[(t & 1) ^ 1][j] = hn;   // 16 consecutive floats per wave
            __syncthreads();
            xt = xnext;
        }
    } else {
        // -------- FC wave: out[t-1] = h_t . W_fc + b_fc + x[t-1], one step deferred --------
        const int   lane = tid - 384;
        const float wfa  = W_fc[lane];
        const float wfb  = (lane < 32) ? W_fc[64 + lane] : 0.0f;
        const float bfc  = b_fc[0];

        float xfc = x[b];                                     // x[(t-1)] for t=1
        for (int t = 0; t < T_STEPS; ++t) {
            const float xnext = x[t * BATCH + b];             // becomes xfc for iter t+1
            if (t > 0) {
                const float* hb = h_buf[t & 1];               // h_t
                float s = hb[lane] * wfa;
                if (lane < 32) s = fmaf(hb[64 + lane], wfb, s);
                #pragma unroll
                for (int d = 1; d < 64; d <<= 1) s += __shfl_xor(s, d);
                if (lane == 0) out[(t - 1) * BATCH + b] = s + bfc + xfc;
            }
            __syncthreads();
            xfc = xnext;
        }
        {   // final timestep: h_T is in h_buf[T&1] (T even -> buf 0)
            const float* hb = h_buf[T_STEPS & 1];
            float s = hb[lane] * wfa;
            if (lane < 32) s = fmaf(hb[64 + lane], wfb, s);
            #pragma unroll
            for (int d = 1; d < 64; d <<= 1) s += __shfl_xor(s, d);
            if (lane == 0) out[(T_STEPS - 1) * BATCH + b] = s + bfc + xfc;
        }
    }
}

extern "C" void kernel_launch(void* const* d_in, const int* in_sizes, int n_in,
                              void* d_out, int out_size, void* d_ws, size_t ws_size,
                              hipStream_t stream) {
    (void)in_sizes; (void)n_in; (void)out_size; (void)d_ws; (void)ws_size;
    const float* x    = (const float*)d_in[0];
    const float* W_ih = (const float*)d_in[1];
    const float* W_hh = (const float*)d_in[2];
    const float* b_ih = (const float*)d_in[3];
    const float* b_hh = (const float*)d_in[4];
    const float* W_fc = (const float*)d_in[5];
    const float* b_fc = (const float*)d_in[6];
    float* out = (float*)d_out;

    lstm_seq_kernel<<<dim3(BATCH), dim3(448), 0, stream>>>(
        x, W_ih, W_hh, b_ih, b_hh, W_fc, b_fc, out);
}

// Round 10
// 4726.254 us; speedup vs baseline: 1.2677x; 1.2239x over previous
//
#include <hip/hip_runtime.h>

#define T_STEPS 8192
#define BATCH   128
#define HID     96

typedef __fp16 h2_t __attribute__((ext_vector_type(2)));

__device__ __forceinline__ unsigned int pk2(float a, float b) {
    return __builtin_bit_cast(unsigned int, __builtin_amdgcn_cvt_pkrtz(a, b));
}
__device__ __forceinline__ float fdot2u(unsigned int w, unsigned int h, float acc) {
    return __builtin_amdgcn_fdot2(__builtin_bit_cast(h2_t, w),
                                  __builtin_bit_cast(h2_t, h), acc, false);
}
__device__ __forceinline__ float fast_sigmoid(float v) {
    return __builtin_amdgcn_rcpf(1.0f + __expf(-v));
}
__device__ __forceinline__ float fast_tanh(float v) {   // 2*sigmoid(2v)-1
    return fmaf(2.0f, __builtin_amdgcn_rcpf(1.0f + __expf(-2.0f * v)), -1.0f);
}

// ---------- prepack W_hh -> f16, THREAD-MAJOR: slot s = j*8 + gp*4 + q owns ----------
// gates {2gp, 2gp+1} of unit j over cols [q*24, q*24+24); 24 contiguous u32 per slot.
__global__ void prepack_kernel(const float* __restrict__ W_hh, unsigned int* __restrict__ wpk) {
    const int i = blockIdx.x * blockDim.x + threadIdx.x;
    if (i < HID * 8 * 24) {
        const int s = i / 24, w = i % 24;
        const int j = s >> 3, gp = (s >> 2) & 1, q = s & 3;
        const int gate = 2 * gp + (w >= 12);
        const int kk   = q * 24 + (w % 12) * 2;
        const float* row = W_hh + (gate * HID + j) * HID;
        wpk[i] = pk2(row[kk], row[kk + 1]);
    }
}

// 768 workers (12 waves) + 1 FC wave = 832 threads. Per-thread weights = 24 u32:
// small enough to live UNDER the ~64-VGPR budget the allocator has enforced in
// every round (R0-R8) -> no spill, no remat, truly register-resident.
__global__ __launch_bounds__(832)
void lstm_seq_kernel(const float* __restrict__ x,
                     const float* __restrict__ W_ih,
                     const float* __restrict__ b_ih,
                     const float* __restrict__ b_hh,
                     const float* __restrict__ W_fc,
                     const float* __restrict__ b_fc,
                     const uint4* __restrict__ ws_u4,   // prepacked f16 W_hh
                     float* __restrict__ out)
{
    const int b   = blockIdx.x;
    const int tid = threadIdx.x;

    __shared__ __align__(16) unsigned int hq[2][48];   // h as f16, double-buffered

    if (tid < 96) ((unsigned int*)hq)[tid] = 0u;
    __syncthreads();

    if (tid < 768) {
        // ---- worker (j, gp, q): gates {2gp,2gp+1} of unit j, cols [q*24, q*24+24) ----
        const int j  = tid >> 3;
        const int gp = (tid >> 2) & 1;
        const int q  = tid & 3;

        const uint4* wp = ws_u4 + tid * 6;        // this thread's 24 contiguous u32
        const uint4 a0 = wp[0], a1 = wp[1], a2 = wp[2];   // gate 2gp
        const uint4 b0 = wp[3], b1 = wp[4], b2 = wp[5];   // gate 2gp+1

        const int rowA = (2 * gp) * HID + j;
        const int rowB = rowA + HID;
        const float wihA = W_ih[rowA], bsA = b_ih[rowA] + b_hh[rowA];
        const float wihB = W_ih[rowB], bsB = b_ih[rowB] + b_hh[rowB];

        float c  = 0.0f;                // replicated across the 8-lane group
        float xt = x[0 * BATCH + b];

        for (int t = 0; t < T_STEPS; ++t) {
            const int   tn    = (t + 1 < T_STEPS) ? (t + 1) : t;
            const float xnext = x[tn * BATCH + b];           // uniform prefetch

            // 24 f16 of h: 3 b128, conflict-free (4 x 48B slices, 16-lane broadcast)
            const uint4* hb = reinterpret_cast<const uint4*>(&hq[t & 1][q * 12]);
            const uint4 h0 = hb[0], h1 = hb[1], h2 = hb[2];

            float accA = (q == 0) ? fmaf(xt, wihA, bsA) : 0.0f;
            float accB = (q == 0) ? fmaf(xt, wihB, bsB) : 0.0f;

            accA = fdot2u(a0.x, h0.x, accA); accA = fdot2u(a0.y, h0.y, accA);
            accA = fdot2u(a0.z, h0.z, accA); accA = fdot2u(a0.w, h0.w, accA);
            accA = fdot2u(a1.x, h1.x, accA); accA = fdot2u(a1.y, h1.y, accA);
            accA = fdot2u(a1.z, h1.z, accA); accA = fdot2u(a1.w, h1.w, accA);
            accA = fdot2u(a2.x, h2.x, accA); accA = fdot2u(a2.y, h2.y, accA);
            accA = fdot2u(a2.z, h2.z, accA); accA = fdot2u(a2.w, h2.w, accA);

            accB = fdot2u(b0.x, h0.x, accB); accB = fdot2u(b0.y, h0.y, accB);
            accB = fdot2u(b0.z, h0.z, accB); accB = fdot2u(b0.w, h0.w, accB);
            accB = fdot2u(b1.x, h1.x, accB); accB = fdot2u(b1.y, h1.y, accB);
            accB = fdot2u(b1.z, h1.z, accB); accB = fdot2u(b1.w, h1.w, accB);
            accB = fdot2u(b2.x, h2.x, accB); accB = fdot2u(b2.y, h2.y, accB);
            accB = fdot2u(b2.z, h2.z, accB); accB = fdot2u(b2.w, h2.w, accB);

            // reduce over q (xor 1,2), then exchange with gate-pair partner (xor 4)
            float sA = accA + __shfl_xor(accA, 1); sA += __shfl_xor(sA, 2);
            float sB = accB + __shfl_xor(accB, 1); sB += __shfl_xor(sB, 2);
            const float oA = __shfl_xor(sA, 4);
            const float oB = __shfl_xor(sB, 4);

            // gp=0 lanes: sA=i sB=f oA=g oB=o ; gp=1 lanes: sA=g sB=o oA=i oB=f
            const float pi = gp ? oA : sA;
            const float pf = gp ? oB : sB;
            const float pg = gp ? sA : oA;
            const float po = gp ? sB : oB;

            const float gi = fast_sigmoid(pi);
            const float gf = fast_sigmoid(pf);
            const float gg = fast_tanh(pg);
            const float go = fast_sigmoid(po);
            c = fmaf(gf, c, gi * gg);
            const float hn = go * fast_tanh(c);

            if ((tid & 7) == 0) ((__fp16*)&hq[(t & 1) ^ 1][0])[j] = (__fp16)hn;
            __syncthreads();
            xt = xnext;
        }
    } else {
        // -------- FC wave (wave 12): out[t-1] = h_t . W_fc + b_fc + x[t-1] --------
        const int   lane = tid - 768;
        const float wfa  = W_fc[lane];
        const float wfb  = (lane < 32) ? W_fc[64 + lane] : 0.0f;
        const float bfc  = b_fc[0];

        float xfc = x[b];                                     // x[t-1] for t=1
        for (int t = 0; t < T_STEPS; ++t) {
            const float xnext = x[t * BATCH + b];
            if (t > 0) {
                const __fp16* hh = (const __fp16*)&hq[t & 1][0];   // h_t
                float s = (float)hh[lane] * wfa;
                if (lane < 32) s = fmaf((float)hh[64 + lane], wfb, s);
                #pragma unroll
                for (int d = 1; d < 64; d <<= 1) s += __shfl_xor(s, d);
                if (lane == 0) out[(t - 1) * BATCH + b] = s + bfc + xfc;
            }
            __syncthreads();
            xfc = xnext;
        }
        {   // final timestep: h_T is in hq[0] (T even)
            const __fp16* hh = (const __fp16*)&hq[T_STEPS & 1][0];
            float s = (float)hh[lane] * wfa;
            if (lane < 32) s = fmaf((float)hh[64 + lane], wfb, s);
            #pragma unroll
            for (int d = 1; d < 64; d <<= 1) s += __shfl_xor(s, d);
            if (lane == 0) out[(T_STEPS - 1) * BATCH + b] = s + bfc + xfc;
        }
    }
}

extern "C" void kernel_launch(void* const* d_in, const int* in_sizes, int n_in,
                              void* d_out, int out_size, void* d_ws, size_t ws_size,
                              hipStream_t stream) {
    (void)in_sizes; (void)n_in; (void)out_size; (void)ws_size;
    const float* x    = (const float*)d_in[0];
    const float* W_ih = (const float*)d_in[1];
    const float* W_hh = (const float*)d_in[2];
    const float* b_ih = (const float*)d_in[3];
    const float* b_hh = (const float*)d_in[4];
    const float* W_fc = (const float*)d_in[5];
    const float* b_fc = (const float*)d_in[6];
    float* out = (float*)d_out;
    unsigned int* wpk = (unsigned int*)d_ws;       // 96*8*24 u32 = 73728 B

    const int npack = HID * 8 * 24;
    prepack_kernel<<<dim3((npack + 255) / 256), dim3(256), 0, stream>>>(W_hh, wpk);

    lstm_seq_kernel<<<dim3(BATCH), dim3(832), 0, stream>>>(
        x, W_ih, b_ih, b_hh, W_fc, b_fc, (const uint4*)wpk, out);
}